// Round 4
// baseline (192.664 us; speedup 1.0000x reference)
//
#include <hip/hip_runtime.h>
#include <cmath>

#define Bz 4
#define Tz 1000
#define Wz 32
#define Dz 200
#define EDz 400
#define Nz 16
#define DTRz 13
#define Lz 1001
#define POSz 500
#define LPz 501
#define TSTR 512
#define NEG_BIG -1e30f

__device__ __forceinline__ float wave_sum(float v) {
#pragma unroll
  for (int o = 32; o; o >>= 1) v += __shfl_xor(v, o);
  return v;
}

// grid = 9 + Bz*Tz blocks.
// blocks 0..8: setup (v[e], CLS row -> xn[POS], z). blocks 9..: word-pool.
__global__ __launch_bounds__(256) void k_front(
    const float* __restrict__ x, const int* __restrict__ n_tweets,
    const int* __restrict__ n_words, const float* __restrict__ w_attn,
    const float* __restrict__ b_attn, const float* __restrict__ norm_w,
    const float* __restrict__ cls, const float* __restrict__ out_proj,
    const float* __restrict__ head_w, const float* __restrict__ ipf,
    const float* __restrict__ ipb, float* __restrict__ xn,
    float* __restrict__ zbuf, float* __restrict__ vbuf) {
  int bid = blockIdx.x;
  int tid = threadIdx.x;
  if (bid < 9) {
    if (bid == 0) {
      __shared__ float hw[Dz];
      if (tid < Dz) hw[tid] = head_w[tid];
      __syncthreads();
      for (int e = tid; e < EDz; e += 256) {
        float acc = 0.f;
        for (int d = 0; d < Dz; d += 4) {
          float4 ov = *(const float4*)(out_proj + e * Dz + d);
          acc += ov.x * hw[d] + ov.y * hw[d + 1] + ov.z * hw[d + 2] + ov.w * hw[d + 3];
        }
        vbuf[e] = acc;
      }
      return;
    }
    int id = bid - 1;
    int br = id >> 2, b = id & 3;
    __shared__ float xs[Dz];
    __shared__ float s_red[4];
    float val = (tid < Dz) ? cls[tid] : 0.f;
    float sq = wave_sum(val * val);
    if ((tid & 63) == 0) s_red[tid >> 6] = sq;
    __syncthreads();
    float tot = s_red[0] + s_red[1] + s_red[2] + s_red[3];
    float scale = rsqrtf(tot * (1.f / Dz) + 1e-5f);
    if (tid < Dz) {
      float o = val * scale * norm_w[tid];
      xs[tid] = o;
      if (br == 0) xn[((size_t)b * Lz + POSz) * Dz + tid] = o;
    }
    __syncthreads();
    const float* ip = br ? ipb : ipf;
    for (int e = tid; e < EDz; e += 256) {
      float acc = 0.f;
      for (int d = 0; d < Dz; ++d) acc += xs[d] * ip[d * (2 * EDz) + EDz + e];
      zbuf[((size_t)br * Bz + b) * EDz + e] = acc;
    }
    return;
  }
  // ---- pool ----
  int blk = bid - 9;
  int b = blk / Tz, t = blk - b * Tz;
  int l = (t < POSz) ? t : t + 1;
  float* outp = xn + ((size_t)b * Lz + l) * Dz;
  int ntw = n_tweets[b]; if (ntw > Tz) ntw = Tz;
  if (t >= ntw) { if (tid < Dz) outp[tid] = 0.f; return; }
  int nw = n_words[b * Tz + t]; if (nw > Wz) nw = Wz; if (nw < 1) nw = 1;
  const float* xs = x + ((size_t)(b * Tz + t)) * (Wz * Dz);
  __shared__ float s_attn[Wz];
  __shared__ float s_red[4];
  int w = tid >> 3, j = tid & 7;
  float sc = 0.f;
  if (w < nw) {
    for (int d = j * 4; d < Dz; d += 32) {
      float4 xv = *(const float4*)(xs + w * Dz + d);
      float4 wv = *(const float4*)(w_attn + d);
      sc += xv.x * wv.x + xv.y * wv.y + xv.z * wv.z + xv.w * wv.w;
    }
  }
  sc += __shfl_xor(sc, 1); sc += __shfl_xor(sc, 2); sc += __shfl_xor(sc, 4);
  if (j == 0) s_attn[w] = (w < nw) ? (sc + b_attn[0]) : NEG_BIG;
  __syncthreads();
  if (tid < 64) {
    float s = (tid < Wz) ? s_attn[tid] : NEG_BIG;
    float m = s;
#pragma unroll
    for (int o = 32; o; o >>= 1) m = fmaxf(m, __shfl_xor(m, o));
    float e = (s > 0.5f * NEG_BIG) ? __expf(s - m) : 0.f;
    float tot = wave_sum(e);
    if (tid < Wz) s_attn[tid] = e / tot;
  }
  __syncthreads();
  float val = 0.f;
  if (tid < Dz) {
    for (int ww = 0; ww < nw; ++ww) val += s_attn[ww] * xs[ww * Dz + tid];
  }
  float sq = wave_sum(val * val);
  if ((tid & 63) == 0) s_red[tid >> 6] = sq;
  __syncthreads();
  float tot = s_red[0] + s_red[1] + s_red[2] + s_red[3];
  float scale = rsqrtf(tot * (1.f / Dz) + 1e-5f);
  if (tid < Dz) outp[tid] = val * scale * norm_w[tid];
}

// Register-tiled GEMM: P^T[brb][e][t] = sum_d W[d][e] * X[t][d].
// 64t x 64e tile per block, 256 threads, 4x4 micro-tile, K-step 16 in LDS.
// X rows with t>500 are zero-masked; no conv here (halo-free).
__global__ __launch_bounds__(256) void k_gemm(
    const float* __restrict__ xn, const float* __restrict__ ipf,
    const float* __restrict__ ipb, float* __restrict__ P) {
  int bid = blockIdx.x;
  int brb = bid / 56;           // 0..7
  int rr = bid - brb * 56;
  int tt = rr / 7, ee = rr - tt * 7;
  int br = brb >> 2, b = brb & 3;
  int t0 = tt * 64, e0 = ee * 64;
  const float* ip = br ? ipb : ipf;
  int tid = threadIdx.x;
  int tx = tid & 15, ty = tid >> 4;

  __shared__ float Xs[16][64 + 4];
  __shared__ float Ws[16][64 + 4];

  float acc[4][4];
#pragma unroll
  for (int i = 0; i < 4; ++i)
#pragma unroll
    for (int j = 0; j < 4; ++j) acc[i][j] = 0.f;

  // staging indices
  int xr = tid >> 2, xc = (tid & 3) * 4;     // X: row (t), 4 cols (d)
  int wr = tid >> 4, wc = (tid & 15) * 4;    // W: row (d), 4 cols (e)
  int t = t0 + xr;
  bool tok = (t < LPz);
  int l = br ? (Lz - 1 - t) : t;             // t <= 511 -> l in-bounds
  const float* xrow = xn + ((size_t)b * Lz + l) * Dz;

  for (int dk = 0; dk < 200; dk += 16) {
    float xv[4], wv[4];
#pragma unroll
    for (int c = 0; c < 4; ++c) {
      int d = dk + xc + c;
      xv[c] = (tok && d < Dz) ? xrow[d] : 0.f;
    }
    int dw = dk + wr;
#pragma unroll
    for (int c = 0; c < 4; ++c) {
      int e = e0 + wc + c;
      wv[c] = (dw < Dz && e < EDz) ? ip[(size_t)dw * (2 * EDz) + e] : 0.f;
    }
    __syncthreads();
#pragma unroll
    for (int c = 0; c < 4; ++c) Xs[xc + c][xr] = xv[c];
#pragma unroll
    for (int c = 0; c < 4; ++c) Ws[wr][wc + c] = wv[c];
    __syncthreads();
#pragma unroll
    for (int k = 0; k < 16; ++k) {
      float4 a4 = *(const float4*)&Xs[k][ty * 4];
      float4 b4 = *(const float4*)&Ws[k][tx * 4];
      float av[4] = {a4.x, a4.y, a4.z, a4.w};
      float bv[4] = {b4.x, b4.y, b4.z, b4.w};
#pragma unroll
      for (int i = 0; i < 4; ++i)
#pragma unroll
        for (int j = 0; j < 4; ++j) acc[i][j] += av[i] * bv[j];
    }
  }
#pragma unroll
  for (int j = 0; j < 4; ++j) {
    int e = e0 + tx * 4 + j;
    if (e < EDz) {
      float4 o = make_float4(acc[0][j], acc[1][j], acc[2][j], acc[3][j]);
      *(float4*)&P[((size_t)brb * EDz + e) * TSTR + t0 + ty * 4] = o;
    }
  }
}

// Per (brb, 64-t chunk): conv+silu -> xp_t ; xproj (45-reg acc per lane,
// lane = t, e-loop coalesced) ; 2-stage LDS cross-wave reduce ; dt ; Bm ; Cend.
__global__ __launch_bounds__(512) void k_post(
    const float* __restrict__ P,
    const float* __restrict__ cwf, const float* __restrict__ cwb,
    const float* __restrict__ cbf, const float* __restrict__ cbb,
    const float* __restrict__ xpjf, const float* __restrict__ xpjb,
    const float* __restrict__ dtwf, const float* __restrict__ dtwb,
    const float* __restrict__ dtbf, const float* __restrict__ dtbb,
    float* __restrict__ xp_t, float* __restrict__ dt_t,
    float* __restrict__ Bm_t, float* __restrict__ Cend) {
  int bid = blockIdx.x;
  int brb = bid >> 3, tc = bid & 7;
  int br = brb >> 2;
  int t0 = tc * 64;
  int tid = threadIdx.x;
  int wave = tid >> 6, lane = tid & 63;
  int t = t0 + lane;
  const float* cw = br ? cwb : cwf;
  const float* cb = br ? cbb : cbf;
  const float* xpj = br ? xpjb : xpjf;
  const float* dtw = br ? dtwb : dtwf;
  const float* dtb = br ? dtbb : dtbf;

  __shared__ float sdbc[4][64][45];

  float accq[45];
#pragma unroll
  for (int q = 0; q < 45; ++q) accq[q] = 0.f;

  const float* Pb = P + (size_t)brb * EDz * TSTR;
  int e_lo = wave * 50, e_hi = e_lo + 50;
  for (int e = e_lo; e < e_hi; ++e) {
    const float* pr = Pb + (size_t)e * TSTR;
    float p[4];
#pragma unroll
    for (int k = 0; k < 4; ++k) {
      int idx = t - 3 + k;
      p[k] = (idx >= 0) ? pr[idx] : 0.f;
    }
    float4 c4 = *(const float4*)(cw + e * 4);
    float a = cb[e] + c4.x * p[0] + c4.y * p[1] + c4.z * p[2] + c4.w * p[3];
    float sp = a / (1.f + __expf(-a));
    xp_t[((size_t)brb * EDz + e) * TSTR + t] = sp;
    const float* xq = xpj + e * 45;
#pragma unroll
    for (int q = 0; q < 45; ++q) accq[q] += sp * xq[q];
  }
  if (wave < 4) {
#pragma unroll
    for (int q = 0; q < 45; ++q) sdbc[wave][lane][q] = accq[q];
  }
  __syncthreads();
  if (wave >= 4) {
#pragma unroll
    for (int q = 0; q < 45; ++q) sdbc[wave - 4][lane][q] += accq[q];
  }
  __syncthreads();

  float dfin[DTRz];
#pragma unroll
  for (int q = 0; q < DTRz; ++q)
    dfin[q] = sdbc[0][lane][q] + sdbc[1][lane][q] + sdbc[2][lane][q] + sdbc[3][lane][q];

  if (wave == 0) {
#pragma unroll
    for (int n = 0; n < Nz; ++n) {
      float bv = sdbc[0][lane][13 + n] + sdbc[1][lane][13 + n] +
                 sdbc[2][lane][13 + n] + sdbc[3][lane][13 + n];
      Bm_t[((size_t)brb * Nz + n) * TSTR + t] = bv;
    }
    if (t == POSz) {
#pragma unroll
      for (int n = 0; n < Nz; ++n) {
        Cend[brb * Nz + n] = sdbc[0][lane][29 + n] + sdbc[1][lane][29 + n] +
                             sdbc[2][lane][29 + n] + sdbc[3][lane][29 + n];
      }
    }
  }

  for (int e = e_lo; e < e_hi; ++e) {
    float s = dtb[e];
#pragma unroll
    for (int q = 0; q < DTRz; ++q) s += dfin[q] * dtw[q * EDz + e];
    float dtv = (s > 20.f) ? s : log1pf(__expf(s));
    dt_t[((size_t)brb * EDz + e) * TSTR + t] = dtv;
  }
}

// h[end,e,n] = sum_t exp(A_n*(Stot-S_t))*dt_t*Bm[t,n]*xp_t, lane-contiguous.
__global__ __launch_bounds__(64) void k_scan(
    const float* __restrict__ xp_t, const float* __restrict__ dt_t,
    const float* __restrict__ Bm_t, const float* __restrict__ Cend,
    const float* __restrict__ Alogf, const float* __restrict__ Alogb,
    const float* __restrict__ Dpf, const float* __restrict__ Dpb,
    const float* __restrict__ zbuf, const float* __restrict__ vbuf,
    float* __restrict__ ybuf) {
  int blk = blockIdx.x;
  int br = blk / (Bz * EDz);
  int rem = blk - br * (Bz * EDz);
  int b = rem / EDz, e = rem - b * EDz;
  int lane = threadIdx.x;
  const float* A_log = br ? Alogb : Alogf;
  const float* Dp = br ? Dpb : Dpf;
  float A[Nz];
  {
    const float4* ap = (const float4*)(A_log + e * Nz);
#pragma unroll
    for (int q = 0; q < 4; ++q) {
      float4 a4 = ap[q];
      A[q * 4 + 0] = -__expf(a4.x); A[q * 4 + 1] = -__expf(a4.y);
      A[q * 4 + 2] = -__expf(a4.z); A[q * 4 + 3] = -__expf(a4.w);
    }
  }
  size_t base = ((size_t)(br * Bz + b) * EDz + e) * TSTR;
  const float* dtp = dt_t + base;
  const float* xpp = xp_t + base;
  const float* bmp = Bm_t + (size_t)(br * Bz + b) * Nz * TSTR;
  float loc = 0.f;
#pragma unroll
  for (int c = 0; c < 8; ++c) {
    int t = c * 64 + lane;
    if (t < LPz) loc += dtp[t];
  }
  float Stot = wave_sum(loc);
  float acc[Nz];
#pragma unroll
  for (int n = 0; n < Nz; ++n) acc[n] = 0.f;
  float carry = 0.f;
  for (int c = 0; c < 8; ++c) {
    int t = c * 64 + lane;
    bool act = t < LPz;
    float dtt = 0.f, xv = 0.f;
    if (act) { dtt = dtp[t]; xv = xpp[t]; }
    float s = dtt;
#pragma unroll
    for (int o = 1; o < 64; o <<= 1) {
      float u = __shfl_up(s, o);
      s += (lane >= o) ? u : 0.f;
    }
    float S = carry + s;
    carry += __shfl(s, 63);
    float wt = dtt * xv;
    float decay = Stot - S;  // >= 0, A<0 => exp<=1
#pragma unroll
    for (int n = 0; n < Nz; ++n) {
      float bv = 0.f;
      if (act) bv = bmp[n * TSTR + t];
      acc[n] += __expf(A[n] * decay) * wt * bv;
    }
  }
#pragma unroll
  for (int o = 32; o; o >>= 1) {
#pragma unroll
    for (int n = 0; n < Nz; ++n) acc[n] += __shfl_xor(acc[n], o);
  }
  if (lane == 0) {
    float y = Dp[e] * xpp[LPz - 1];
#pragma unroll
    for (int n = 0; n < Nz; ++n) y += Cend[(br * Bz + b) * Nz + n] * acc[n];
    float zz = zbuf[((size_t)br * Bz + b) * EDz + e];
    float sz = zz / (1.f + __expf(-zz));
    ybuf[((size_t)br * Bz + b) * EDz + e] = y * sz * vbuf[e];
  }
}

__global__ __launch_bounds__(256) void k_final(
    const float* __restrict__ cls, const float* __restrict__ head_w,
    const float* __restrict__ head_b, const float* __restrict__ ybuf,
    float* __restrict__ out) {
  int tid = threadIdx.x;
  int b = tid >> 6, lane = tid & 63;
  float acc = 0.f;
  for (int e = lane; e < EDz; e += 64)
    acc += ybuf[(size_t)b * EDz + e] + ybuf[(size_t)(Bz + b) * EDz + e];
  for (int d = lane; d < Dz; d += 64) acc += cls[d] * head_w[d];
  acc = wave_sum(acc);
  if (lane == 0) out[b] = 1.f / (1.f + __expf(-(acc + head_b[0])));
}

extern "C" void kernel_launch(void* const* d_in, const int* in_sizes, int n_in,
                              void* d_out, int out_size, void* d_ws, size_t ws_size,
                              hipStream_t stream) {
  const float* input_ids = (const float*)d_in[0];
  const int* n_tweets = (const int*)d_in[1];
  const int* n_words = (const int*)d_in[2];
  const float* cls = (const float*)d_in[3];
  const float* w_attn = (const float*)d_in[4];
  const float* b_attn = (const float*)d_in[5];
  const float* norm_w = (const float*)d_in[6];
  const float* ip[2] = {(const float*)d_in[7], (const float*)d_in[15]};
  const float* cw[2] = {(const float*)d_in[8], (const float*)d_in[16]};
  const float* cb[2] = {(const float*)d_in[9], (const float*)d_in[17]};
  const float* xpj[2] = {(const float*)d_in[10], (const float*)d_in[18]};
  const float* dtw[2] = {(const float*)d_in[11], (const float*)d_in[19]};
  const float* dtbp[2] = {(const float*)d_in[12], (const float*)d_in[20]};
  const float* Alog[2] = {(const float*)d_in[13], (const float*)d_in[21]};
  const float* Dpp[2] = {(const float*)d_in[14], (const float*)d_in[22]};
  const float* out_proj = (const float*)d_in[23];
  const float* head_w = (const float*)d_in[24];
  const float* head_b = (const float*)d_in[25];
  float* out = (float*)d_out;

  float* ws = (float*)d_ws;
  float* xn = ws;                           // 800800
  float* Pbuf = xn + 800800;                // 2*4*400*512 = 1638400
  float* xp_t = Pbuf + 1638400;             // 1638400
  float* dt_t = xp_t + 1638400;             // 1638400
  float* Bm_t = dt_t + 1638400;             // 65536
  float* Cend = Bm_t + 65536;               // 128
  float* zbuf = Cend + 128;                 // 3200
  float* vbuf = zbuf + 3200;                // 400
  float* ybuf = vbuf + 400;                 // 3200
  // total ~5.8M floats ~23.2 MB

  hipLaunchKernelGGL(k_front, dim3(9 + Bz * Tz), dim3(256), 0, stream,
                     input_ids, n_tweets, n_words, w_attn, b_attn, norm_w,
                     cls, out_proj, head_w, ip[0], ip[1], xn, zbuf, vbuf);
  hipLaunchKernelGGL(k_gemm, dim3(2 * Bz * 8 * 7), dim3(256), 0, stream,
                     xn, ip[0], ip[1], Pbuf);
  hipLaunchKernelGGL(k_post, dim3(2 * Bz * 8), dim3(512), 0, stream,
                     Pbuf, cw[0], cw[1], cb[0], cb[1], xpj[0], xpj[1],
                     dtw[0], dtw[1], dtbp[0], dtbp[1],
                     xp_t, dt_t, Bm_t, Cend);
  hipLaunchKernelGGL(k_scan, dim3(2 * Bz * EDz), dim3(64), 0, stream,
                     xp_t, dt_t, Bm_t, Cend, Alog[0], Alog[1], Dpp[0], Dpp[1],
                     zbuf, vbuf, ybuf);
  hipLaunchKernelGGL(k_final, dim3(1), dim3(256), 0, stream,
                     cls, head_w, head_b, ybuf, out);
}

// Round 5
// 159.751 us; speedup vs baseline: 1.2060x; 1.2060x over previous
//
#include <hip/hip_runtime.h>
#include <cmath>

#define Bz 4
#define Tz 1000
#define Wz 32
#define Dz 200
#define EDz 400
#define Nz 16
#define DTRz 13
#define Lz 1001
#define POSz 500
#define LPz 501
#define TSTR 512
#define ESP 10      // e-splits in k_mid (40 e each)
#define NEG_BIG -1e30f

__device__ __forceinline__ float wave_sum(float v) {
#pragma unroll
  for (int o = 32; o; o >>= 1) v += __shfl_xor(v, o);
  return v;
}

// grid = 9 + Bz*Tz blocks.
// blocks 0..8: setup (v[e], CLS row -> xn[POS], z). blocks 9..: word-pool.
__global__ __launch_bounds__(256) void k_front(
    const float* __restrict__ x, const int* __restrict__ n_tweets,
    const int* __restrict__ n_words, const float* __restrict__ w_attn,
    const float* __restrict__ b_attn, const float* __restrict__ norm_w,
    const float* __restrict__ cls, const float* __restrict__ out_proj,
    const float* __restrict__ head_w, const float* __restrict__ ipf,
    const float* __restrict__ ipb, float* __restrict__ xn,
    float* __restrict__ zbuf, float* __restrict__ vbuf) {
  int bid = blockIdx.x;
  int tid = threadIdx.x;
  if (bid < 9) {
    if (bid == 0) {
      __shared__ float hw[Dz];
      if (tid < Dz) hw[tid] = head_w[tid];
      __syncthreads();
      for (int e = tid; e < EDz; e += 256) {
        float acc = 0.f;
        for (int d = 0; d < Dz; d += 4) {
          float4 ov = *(const float4*)(out_proj + e * Dz + d);
          acc += ov.x * hw[d] + ov.y * hw[d + 1] + ov.z * hw[d + 2] + ov.w * hw[d + 3];
        }
        vbuf[e] = acc;
      }
      return;
    }
    int id = bid - 1;
    int br = id >> 2, b = id & 3;
    __shared__ float xs[Dz];
    __shared__ float s_red[4];
    float val = (tid < Dz) ? cls[tid] : 0.f;
    float sq = wave_sum(val * val);
    if ((tid & 63) == 0) s_red[tid >> 6] = sq;
    __syncthreads();
    float tot = s_red[0] + s_red[1] + s_red[2] + s_red[3];
    float scale = rsqrtf(tot * (1.f / Dz) + 1e-5f);
    if (tid < Dz) {
      float o = val * scale * norm_w[tid];
      xs[tid] = o;
      if (br == 0) xn[((size_t)b * Lz + POSz) * Dz + tid] = o;
    }
    __syncthreads();
    const float* ip = br ? ipb : ipf;
    for (int e = tid; e < EDz; e += 256) {
      float acc = 0.f;
      for (int d = 0; d < Dz; ++d) acc += xs[d] * ip[d * (2 * EDz) + EDz + e];
      zbuf[((size_t)br * Bz + b) * EDz + e] = acc;
    }
    return;
  }
  // ---- pool ----
  int blk = bid - 9;
  int b = blk / Tz, t = blk - b * Tz;
  int l = (t < POSz) ? t : t + 1;
  float* outp = xn + ((size_t)b * Lz + l) * Dz;
  int ntw = n_tweets[b]; if (ntw > Tz) ntw = Tz;
  if (t >= ntw) { if (tid < Dz) outp[tid] = 0.f; return; }
  int nw = n_words[b * Tz + t]; if (nw > Wz) nw = Wz; if (nw < 1) nw = 1;
  const float* xs = x + ((size_t)(b * Tz + t)) * (Wz * Dz);
  __shared__ float s_attn[Wz];
  __shared__ float s_red[4];
  int w = tid >> 3, j = tid & 7;
  float sc = 0.f;
  if (w < nw) {
    for (int d = j * 4; d < Dz; d += 32) {
      float4 xv = *(const float4*)(xs + w * Dz + d);
      float4 wv = *(const float4*)(w_attn + d);
      sc += xv.x * wv.x + xv.y * wv.y + xv.z * wv.z + xv.w * wv.w;
    }
  }
  sc += __shfl_xor(sc, 1); sc += __shfl_xor(sc, 2); sc += __shfl_xor(sc, 4);
  if (j == 0) s_attn[w] = (w < nw) ? (sc + b_attn[0]) : NEG_BIG;
  __syncthreads();
  if (tid < 64) {
    float s = (tid < Wz) ? s_attn[tid] : NEG_BIG;
    float m = s;
#pragma unroll
    for (int o = 32; o; o >>= 1) m = fmaxf(m, __shfl_xor(m, o));
    float e = (s > 0.5f * NEG_BIG) ? __expf(s - m) : 0.f;
    float tot = wave_sum(e);
    if (tid < Wz) s_attn[tid] = e / tot;
  }
  __syncthreads();
  float val = 0.f;
  if (tid < Dz) {
    for (int ww = 0; ww < nw; ++ww) val += s_attn[ww] * xs[ww * Dz + tid];
  }
  float sq = wave_sum(val * val);
  if ((tid & 63) == 0) s_red[tid >> 6] = sq;
  __syncthreads();
  float tot = s_red[0] + s_red[1] + s_red[2] + s_red[3];
  float scale = rsqrtf(tot * (1.f / Dz) + 1e-5f);
  if (tid < Dz) outp[tid] = val * scale * norm_w[tid];
}

// Register-tiled GEMM: P^T[brb][e][t] = sum_d W[d][e] * X[t][d].
// 64t x 64e tile per block, 256 threads, 4x4 micro-tile, K-step 16 in LDS.
__global__ __launch_bounds__(256) void k_gemm(
    const float* __restrict__ xn, const float* __restrict__ ipf,
    const float* __restrict__ ipb, float* __restrict__ P) {
  int bid = blockIdx.x;
  int brb = bid / 56;
  int rr = bid - brb * 56;
  int tt = rr / 7, ee = rr - tt * 7;
  int br = brb >> 2, b = brb & 3;
  int t0 = tt * 64, e0 = ee * 64;
  const float* ip = br ? ipb : ipf;
  int tid = threadIdx.x;
  int tx = tid & 15, ty = tid >> 4;

  __shared__ float Xs[16][64 + 4];
  __shared__ float Ws[16][64 + 4];

  float acc[4][4];
#pragma unroll
  for (int i = 0; i < 4; ++i)
#pragma unroll
    for (int j = 0; j < 4; ++j) acc[i][j] = 0.f;

  int xr = tid >> 2, xc = (tid & 3) * 4;
  int wr = tid >> 4, wc = (tid & 15) * 4;
  int t = t0 + xr;
  bool tok = (t < LPz);
  int l = br ? (Lz - 1 - t) : t;
  const float* xrow = xn + ((size_t)b * Lz + l) * Dz;

  for (int dk = 0; dk < 200; dk += 16) {
    float xv[4], wv[4];
#pragma unroll
    for (int c = 0; c < 4; ++c) {
      int d = dk + xc + c;
      xv[c] = (tok && d < Dz) ? xrow[d] : 0.f;
    }
    int dw = dk + wr;
#pragma unroll
    for (int c = 0; c < 4; ++c) {
      int e = e0 + wc + c;
      wv[c] = (dw < Dz && e < EDz) ? ip[(size_t)dw * (2 * EDz) + e] : 0.f;
    }
    __syncthreads();
#pragma unroll
    for (int c = 0; c < 4; ++c) Xs[xc + c][xr] = xv[c];
#pragma unroll
    for (int c = 0; c < 4; ++c) Ws[wr][wc + c] = wv[c];
    __syncthreads();
#pragma unroll
    for (int k = 0; k < 16; ++k) {
      float4 a4 = *(const float4*)&Xs[k][ty * 4];
      float4 b4 = *(const float4*)&Ws[k][tx * 4];
      float av[4] = {a4.x, a4.y, a4.z, a4.w};
      float bv[4] = {b4.x, b4.y, b4.z, b4.w};
#pragma unroll
      for (int i = 0; i < 4; ++i)
#pragma unroll
        for (int j = 0; j < 4; ++j) acc[i][j] += av[i] * bv[j];
    }
  }
#pragma unroll
  for (int j = 0; j < 4; ++j) {
    int e = e0 + tx * 4 + j;
    if (e < EDz) {
      float4 o = make_float4(acc[0][j], acc[1][j], acc[2][j], acc[3][j]);
      *(float4*)&P[((size_t)brb * EDz + e) * TSTR + t0 + ty * 4] = o;
    }
  }
}

// conv+silu -> xp_t ; xproj partial over 40 e's -> dbcpart[esp][brb][45][t].
// grid = brb(8) x tchunk(8) x esp(10) = 640 blocks, 256 threads (4 waves).
__global__ __launch_bounds__(256) void k_mid(
    const float* __restrict__ P,
    const float* __restrict__ cwf, const float* __restrict__ cwb,
    const float* __restrict__ cbf, const float* __restrict__ cbb,
    const float* __restrict__ xpjf, const float* __restrict__ xpjb,
    float* __restrict__ xp_t, float* __restrict__ dbcp) {
  int bid = blockIdx.x;
  int esp = bid % ESP;
  int rem = bid / ESP;
  int tc = rem & 7, brb = rem >> 3;
  int br = brb >> 2;
  int tid = threadIdx.x;
  int wave = tid >> 6, lane = tid & 63;
  int t = tc * 64 + lane;
  const float* cw = br ? cwb : cwf;
  const float* cb = br ? cbb : cbf;
  const float* xpj = br ? xpjb : xpjf;

  __shared__ float sred[4][64][45];

  float accq[45];
#pragma unroll
  for (int q = 0; q < 45; ++q) accq[q] = 0.f;

  const float* Pb = P + (size_t)brb * EDz * TSTR;
  int e0 = esp * 40 + wave * 10;
#pragma unroll 2
  for (int i = 0; i < 10; ++i) {
    int e = e0 + i;
    const float* pr = Pb + (size_t)e * TSTR;
    float p0 = (t >= 3) ? pr[t - 3] : 0.f;
    float p1 = (t >= 2) ? pr[t - 2] : 0.f;
    float p2 = (t >= 1) ? pr[t - 1] : 0.f;
    float p3 = pr[t];
    float4 c4 = *(const float4*)(cw + e * 4);
    float a = cb[e] + c4.x * p0 + c4.y * p1 + c4.z * p2 + c4.w * p3;
    float sp = a / (1.f + __expf(-a));
    xp_t[((size_t)brb * EDz + e) * TSTR + t] = sp;
    const float* xq = xpj + e * 45;
#pragma unroll
    for (int q = 0; q < 45; ++q) accq[q] += sp * xq[q];
  }
#pragma unroll
  for (int q = 0; q < 45; ++q) sred[wave][lane][q] = accq[q];
  __syncthreads();
  if (wave < 2) {
#pragma unroll
    for (int q = 0; q < 45; ++q)
      sred[wave][lane][q] += sred[wave + 2][lane][q];
  }
  __syncthreads();
  if (wave == 0) {
    float* dp = dbcp + ((size_t)(esp * 8 + brb) * 45) * TSTR + t;
#pragma unroll
    for (int q = 0; q < 45; ++q)
      dp[(size_t)q * TSTR] = sred[0][lane][q] + sred[1][lane][q];
  }
}

// Sum ESP partials -> dfin[t][45]; dt = softplus(dtb + dfin@dtw); Bm_t, Cend.
// grid = brb(8) x tchunk(8) = 64 blocks, 256 threads.
__global__ __launch_bounds__(256) void k_dt(
    const float* __restrict__ dbcp,
    const float* __restrict__ dtwf, const float* __restrict__ dtwb,
    const float* __restrict__ dtbf, const float* __restrict__ dtbb,
    float* __restrict__ dt_t, float* __restrict__ Bm_t,
    float* __restrict__ Cend) {
  int bid = blockIdx.x;
  int tc = bid & 7, brb = bid >> 3;
  int br = brb >> 2;
  int tid = threadIdx.x;
  int grp = tid >> 6, lane = tid & 63;
  int t = tc * 64 + lane;
  const float* dtw = br ? dtwb : dtwf;
  const float* dtb = br ? dtbb : dtbf;

  __shared__ float dfin[64][45];

  for (int idx = tid; idx < 45 * 64; idx += 256) {
    int q = idx >> 6, tl = idx & 63;
    size_t base = ((size_t)brb * 45 + q) * TSTR + tc * 64 + tl;
    float s = 0.f;
#pragma unroll
    for (int esp = 0; esp < ESP; ++esp)
      s += dbcp[base + (size_t)esp * 8 * 45 * TSTR];
    dfin[tl][q] = s;
  }
  __syncthreads();

  float dq[DTRz];
#pragma unroll
  for (int q = 0; q < DTRz; ++q) dq[q] = dfin[lane][q];

  for (int i = 0; i < 100; ++i) {
    int e = grp * 100 + i;
    float s = dtb[e];
#pragma unroll
    for (int q = 0; q < DTRz; ++q) s += dq[q] * dtw[q * EDz + e];
    float dtv = (s > 20.f) ? s : log1pf(__expf(s));
    dt_t[((size_t)brb * EDz + e) * TSTR + t] = dtv;
  }
  if (grp == 0) {
#pragma unroll
    for (int n = 0; n < Nz; ++n)
      Bm_t[((size_t)brb * Nz + n) * TSTR + t] = dfin[lane][13 + n];
  }
  if (grp == 1 && t == POSz) {
#pragma unroll
    for (int n = 0; n < Nz; ++n) Cend[brb * Nz + n] = dfin[lane][29 + n];
  }
}

// h[end,e,n] = sum_t exp(A_n*(Stot-S_t))*dt_t*Bm[t,n]*xp_t, lane-contiguous.
__global__ __launch_bounds__(64) void k_scan(
    const float* __restrict__ xp_t, const float* __restrict__ dt_t,
    const float* __restrict__ Bm_t, const float* __restrict__ Cend,
    const float* __restrict__ Alogf, const float* __restrict__ Alogb,
    const float* __restrict__ Dpf, const float* __restrict__ Dpb,
    const float* __restrict__ zbuf, const float* __restrict__ vbuf,
    float* __restrict__ ybuf) {
  int blk = blockIdx.x;
  int br = blk / (Bz * EDz);
  int rem = blk - br * (Bz * EDz);
  int b = rem / EDz, e = rem - b * EDz;
  int lane = threadIdx.x;
  const float* A_log = br ? Alogb : Alogf;
  const float* Dp = br ? Dpb : Dpf;
  float A[Nz];
  {
    const float4* ap = (const float4*)(A_log + e * Nz);
#pragma unroll
    for (int q = 0; q < 4; ++q) {
      float4 a4 = ap[q];
      A[q * 4 + 0] = -__expf(a4.x); A[q * 4 + 1] = -__expf(a4.y);
      A[q * 4 + 2] = -__expf(a4.z); A[q * 4 + 3] = -__expf(a4.w);
    }
  }
  size_t base = ((size_t)(br * Bz + b) * EDz + e) * TSTR;
  const float* dtp = dt_t + base;
  const float* xpp = xp_t + base;
  const float* bmp = Bm_t + (size_t)(br * Bz + b) * Nz * TSTR;
  float loc = 0.f;
#pragma unroll
  for (int c = 0; c < 8; ++c) {
    int t = c * 64 + lane;
    if (t < LPz) loc += dtp[t];
  }
  float Stot = wave_sum(loc);
  float acc[Nz];
#pragma unroll
  for (int n = 0; n < Nz; ++n) acc[n] = 0.f;
  float carry = 0.f;
  for (int c = 0; c < 8; ++c) {
    int t = c * 64 + lane;
    bool act = t < LPz;
    float dtt = 0.f, xv = 0.f;
    if (act) { dtt = dtp[t]; xv = xpp[t]; }
    float s = dtt;
#pragma unroll
    for (int o = 1; o < 64; o <<= 1) {
      float u = __shfl_up(s, o);
      s += (lane >= o) ? u : 0.f;
    }
    float S = carry + s;
    carry += __shfl(s, 63);
    float wt = dtt * xv;
    float decay = Stot - S;  // >= 0, A<0 => exp<=1
#pragma unroll
    for (int n = 0; n < Nz; ++n) {
      float bv = 0.f;
      if (act) bv = bmp[n * TSTR + t];
      acc[n] += __expf(A[n] * decay) * wt * bv;
    }
  }
#pragma unroll
  for (int o = 32; o; o >>= 1) {
#pragma unroll
    for (int n = 0; n < Nz; ++n) acc[n] += __shfl_xor(acc[n], o);
  }
  if (lane == 0) {
    float y = Dp[e] * xpp[LPz - 1];
#pragma unroll
    for (int n = 0; n < Nz; ++n) y += Cend[(br * Bz + b) * Nz + n] * acc[n];
    float zz = zbuf[((size_t)br * Bz + b) * EDz + e];
    float sz = zz / (1.f + __expf(-zz));
    ybuf[((size_t)br * Bz + b) * EDz + e] = y * sz * vbuf[e];
  }
}

__global__ __launch_bounds__(256) void k_final(
    const float* __restrict__ cls, const float* __restrict__ head_w,
    const float* __restrict__ head_b, const float* __restrict__ ybuf,
    float* __restrict__ out) {
  int tid = threadIdx.x;
  int b = tid >> 6, lane = tid & 63;
  float acc = 0.f;
  for (int e = lane; e < EDz; e += 64)
    acc += ybuf[(size_t)b * EDz + e] + ybuf[(size_t)(Bz + b) * EDz + e];
  for (int d = lane; d < Dz; d += 64) acc += cls[d] * head_w[d];
  acc = wave_sum(acc);
  if (lane == 0) out[b] = 1.f / (1.f + __expf(-(acc + head_b[0])));
}

extern "C" void kernel_launch(void* const* d_in, const int* in_sizes, int n_in,
                              void* d_out, int out_size, void* d_ws, size_t ws_size,
                              hipStream_t stream) {
  const float* input_ids = (const float*)d_in[0];
  const int* n_tweets = (const int*)d_in[1];
  const int* n_words = (const int*)d_in[2];
  const float* cls = (const float*)d_in[3];
  const float* w_attn = (const float*)d_in[4];
  const float* b_attn = (const float*)d_in[5];
  const float* norm_w = (const float*)d_in[6];
  const float* ip[2] = {(const float*)d_in[7], (const float*)d_in[15]};
  const float* cw[2] = {(const float*)d_in[8], (const float*)d_in[16]};
  const float* cb[2] = {(const float*)d_in[9], (const float*)d_in[17]};
  const float* xpj[2] = {(const float*)d_in[10], (const float*)d_in[18]};
  const float* dtw[2] = {(const float*)d_in[11], (const float*)d_in[19]};
  const float* dtbp[2] = {(const float*)d_in[12], (const float*)d_in[20]};
  const float* Alog[2] = {(const float*)d_in[13], (const float*)d_in[21]};
  const float* Dpp[2] = {(const float*)d_in[14], (const float*)d_in[22]};
  const float* out_proj = (const float*)d_in[23];
  const float* head_w = (const float*)d_in[24];
  const float* head_b = (const float*)d_in[25];
  float* out = (float*)d_out;

  float* ws = (float*)d_ws;
  float* xn = ws;                           // 800800
  float* Pbuf = xn + 800800;                // 1638400
  float* xp_t = Pbuf + 1638400;             // 1638400
  float* dt_t = xp_t + 1638400;             // 1638400
  float* Bm_t = dt_t + 1638400;             // 65536
  float* dbcp = Bm_t + 65536;               // 10*8*45*512 = 1843200
  float* Cend = dbcp + 1843200;             // 128
  float* zbuf = Cend + 128;                 // 3200
  float* vbuf = zbuf + 3200;                // 400
  float* ybuf = vbuf + 400;                 // 3200
  // total ~7.63M floats ~30.5 MB

  hipLaunchKernelGGL(k_front, dim3(9 + Bz * Tz), dim3(256), 0, stream,
                     input_ids, n_tweets, n_words, w_attn, b_attn, norm_w,
                     cls, out_proj, head_w, ip[0], ip[1], xn, zbuf, vbuf);
  hipLaunchKernelGGL(k_gemm, dim3(2 * Bz * 8 * 7), dim3(256), 0, stream,
                     xn, ip[0], ip[1], Pbuf);
  hipLaunchKernelGGL(k_mid, dim3(2 * Bz * 8 * ESP), dim3(256), 0, stream,
                     Pbuf, cw[0], cw[1], cb[0], cb[1], xpj[0], xpj[1],
                     xp_t, dbcp);
  hipLaunchKernelGGL(k_dt, dim3(2 * Bz * 8), dim3(256), 0, stream,
                     dbcp, dtw[0], dtw[1], dtbp[0], dtbp[1],
                     dt_t, Bm_t, Cend);
  hipLaunchKernelGGL(k_scan, dim3(2 * Bz * EDz), dim3(64), 0, stream,
                     xp_t, dt_t, Bm_t, Cend, Alog[0], Alog[1], Dpp[0], Dpp[1],
                     zbuf, vbuf, ybuf);
  hipLaunchKernelGGL(k_final, dim3(1), dim3(256), 0, stream,
                     cls, head_w, head_b, ybuf, out);
}

// Round 6
// 106.925 us; speedup vs baseline: 1.8019x; 1.4940x over previous
//
#include <hip/hip_runtime.h>
#include <cmath>

#define Bz 4
#define Tz 1000
#define Wz 32
#define Dz 200
#define EDz 400
#define Nz 16
#define DTRz 13
#define Lz 1001
#define POSz 500
#define LPz 501
#define TSTR 512
#define ESP 10      // e-splits in k_mid (40 e each)
#define NEG_BIG -1e30f

__device__ __forceinline__ float wave_sum(float v) {
#pragma unroll
  for (int o = 32; o; o >>= 1) v += __shfl_xor(v, o);
  return v;
}

// grid = 9 + Bz*Tz blocks.
// blocks 0..8: setup (v[e], CLS row -> xn[POS], z). blocks 9..: word-pool.
__global__ __launch_bounds__(256) void k_front(
    const float* __restrict__ x, const int* __restrict__ n_tweets,
    const int* __restrict__ n_words, const float* __restrict__ w_attn,
    const float* __restrict__ b_attn, const float* __restrict__ norm_w,
    const float* __restrict__ cls, const float* __restrict__ out_proj,
    const float* __restrict__ head_w, const float* __restrict__ ipf,
    const float* __restrict__ ipb, float* __restrict__ xn,
    float* __restrict__ zbuf, float* __restrict__ vbuf) {
  int bid = blockIdx.x;
  int tid = threadIdx.x;
  if (bid < 9) {
    if (bid == 0) {
      __shared__ float hw[Dz];
      if (tid < Dz) hw[tid] = head_w[tid];
      __syncthreads();
      for (int e = tid; e < EDz; e += 256) {
        float acc = 0.f;
        for (int d = 0; d < Dz; d += 4) {
          float4 ov = *(const float4*)(out_proj + e * Dz + d);
          acc += ov.x * hw[d] + ov.y * hw[d + 1] + ov.z * hw[d + 2] + ov.w * hw[d + 3];
        }
        vbuf[e] = acc;
      }
      return;
    }
    int id = bid - 1;
    int br = id >> 2, b = id & 3;
    __shared__ float xs[Dz];
    __shared__ float s_red[4];
    float val = (tid < Dz) ? cls[tid] : 0.f;
    float sq = wave_sum(val * val);
    if ((tid & 63) == 0) s_red[tid >> 6] = sq;
    __syncthreads();
    float tot = s_red[0] + s_red[1] + s_red[2] + s_red[3];
    float scale = rsqrtf(tot * (1.f / Dz) + 1e-5f);
    if (tid < Dz) {
      float o = val * scale * norm_w[tid];
      xs[tid] = o;
      if (br == 0) xn[((size_t)b * Lz + POSz) * Dz + tid] = o;
    }
    __syncthreads();
    const float* ip = br ? ipb : ipf;
    for (int e = tid; e < EDz; e += 256) {
      float acc = 0.f;
      for (int d = 0; d < Dz; ++d) acc += xs[d] * ip[d * (2 * EDz) + EDz + e];
      zbuf[((size_t)br * Bz + b) * EDz + e] = acc;
    }
    return;
  }
  // ---- pool ----
  int blk = bid - 9;
  int b = blk / Tz, t = blk - b * Tz;
  int l = (t < POSz) ? t : t + 1;
  float* outp = xn + ((size_t)b * Lz + l) * Dz;
  int ntw = n_tweets[b]; if (ntw > Tz) ntw = Tz;
  if (t >= ntw) { if (tid < Dz) outp[tid] = 0.f; return; }
  int nw = n_words[b * Tz + t]; if (nw > Wz) nw = Wz; if (nw < 1) nw = 1;
  const float* xs = x + ((size_t)(b * Tz + t)) * (Wz * Dz);
  __shared__ float s_attn[Wz];
  __shared__ float s_red[4];
  int w = tid >> 3, j = tid & 7;
  float sc = 0.f;
  if (w < nw) {
    for (int d = j * 4; d < Dz; d += 32) {
      float4 xv = *(const float4*)(xs + w * Dz + d);
      float4 wv = *(const float4*)(w_attn + d);
      sc += xv.x * wv.x + xv.y * wv.y + xv.z * wv.z + xv.w * wv.w;
    }
  }
  sc += __shfl_xor(sc, 1); sc += __shfl_xor(sc, 2); sc += __shfl_xor(sc, 4);
  if (j == 0) s_attn[w] = (w < nw) ? (sc + b_attn[0]) : NEG_BIG;
  __syncthreads();
  if (tid < 64) {
    float s = (tid < Wz) ? s_attn[tid] : NEG_BIG;
    float m = s;
#pragma unroll
    for (int o = 32; o; o >>= 1) m = fmaxf(m, __shfl_xor(m, o));
    float e = (s > 0.5f * NEG_BIG) ? __expf(s - m) : 0.f;
    float tot = wave_sum(e);
    if (tid < Wz) s_attn[tid] = e / tot;
  }
  __syncthreads();
  float val = 0.f;
  if (tid < Dz) {
    for (int ww = 0; ww < nw; ++ww) val += s_attn[ww] * xs[ww * Dz + tid];
  }
  float sq = wave_sum(val * val);
  if ((tid & 63) == 0) s_red[tid >> 6] = sq;
  __syncthreads();
  float tot = s_red[0] + s_red[1] + s_red[2] + s_red[3];
  float scale = rsqrtf(tot * (1.f / Dz) + 1e-5f);
  if (tid < Dz) outp[tid] = val * scale * norm_w[tid];
}

// Register-tiled GEMM: P^T[brb][e][t] = sum_d W[d][e] * X[t][d].
// 64t x 64e tile per block, 256 threads, 4x4 micro-tile, K-step 16 in LDS.
__global__ __launch_bounds__(256) void k_gemm(
    const float* __restrict__ xn, const float* __restrict__ ipf,
    const float* __restrict__ ipb, float* __restrict__ P) {
  int bid = blockIdx.x;
  int brb = bid / 56;
  int rr = bid - brb * 56;
  int tt = rr / 7, ee = rr - tt * 7;
  int br = brb >> 2, b = brb & 3;
  int t0 = tt * 64, e0 = ee * 64;
  const float* ip = br ? ipb : ipf;
  int tid = threadIdx.x;
  int tx = tid & 15, ty = tid >> 4;

  __shared__ float Xs[16][64 + 4];
  __shared__ float Ws[16][64 + 4];

  float acc[4][4];
#pragma unroll
  for (int i = 0; i < 4; ++i)
#pragma unroll
    for (int j = 0; j < 4; ++j) acc[i][j] = 0.f;

  int xr = tid >> 2, xc = (tid & 3) * 4;
  int wr = tid >> 4, wc = (tid & 15) * 4;
  int t = t0 + xr;
  bool tok = (t < LPz);
  int l = br ? (Lz - 1 - t) : t;
  const float* xrow = xn + ((size_t)b * Lz + l) * Dz;

  for (int dk = 0; dk < 200; dk += 16) {
    float xv[4], wv[4];
#pragma unroll
    for (int c = 0; c < 4; ++c) {
      int d = dk + xc + c;
      xv[c] = (tok && d < Dz) ? xrow[d] : 0.f;
    }
    int dw = dk + wr;
#pragma unroll
    for (int c = 0; c < 4; ++c) {
      int e = e0 + wc + c;
      wv[c] = (dw < Dz && e < EDz) ? ip[(size_t)dw * (2 * EDz) + e] : 0.f;
    }
    __syncthreads();
#pragma unroll
    for (int c = 0; c < 4; ++c) Xs[xc + c][xr] = xv[c];
#pragma unroll
    for (int c = 0; c < 4; ++c) Ws[wr][wc + c] = wv[c];
    __syncthreads();
#pragma unroll
    for (int k = 0; k < 16; ++k) {
      float4 a4 = *(const float4*)&Xs[k][ty * 4];
      float4 b4 = *(const float4*)&Ws[k][tx * 4];
      float av[4] = {a4.x, a4.y, a4.z, a4.w};
      float bv[4] = {b4.x, b4.y, b4.z, b4.w};
#pragma unroll
      for (int i = 0; i < 4; ++i)
#pragma unroll
        for (int j = 0; j < 4; ++j) acc[i][j] += av[i] * bv[j];
    }
  }
#pragma unroll
  for (int j = 0; j < 4; ++j) {
    int e = e0 + tx * 4 + j;
    if (e < EDz) {
      float4 o = make_float4(acc[0][j], acc[1][j], acc[2][j], acc[3][j]);
      *(float4*)&P[((size_t)brb * EDz + e) * TSTR + t0 + ty * 4] = o;
    }
  }
}

// conv+silu -> xp_t ; xproj partial over 40 e's -> dbcpart[esp][brb][45][t].
// grid = brb(8) x tchunk(8) x esp(10) = 640 blocks, 256 threads (4 waves).
__global__ __launch_bounds__(256) void k_mid(
    const float* __restrict__ P,
    const float* __restrict__ cwf, const float* __restrict__ cwb,
    const float* __restrict__ cbf, const float* __restrict__ cbb,
    const float* __restrict__ xpjf, const float* __restrict__ xpjb,
    float* __restrict__ xp_t, float* __restrict__ dbcp) {
  int bid = blockIdx.x;
  int esp = bid % ESP;
  int rem = bid / ESP;
  int tc = rem & 7, brb = rem >> 3;
  int br = brb >> 2;
  int tid = threadIdx.x;
  int wave = tid >> 6, lane = tid & 63;
  int t = tc * 64 + lane;
  const float* cw = br ? cwb : cwf;
  const float* cb = br ? cbb : cbf;
  const float* xpj = br ? xpjb : xpjf;

  __shared__ float sred[4][64][45];

  float accq[45];
#pragma unroll
  for (int q = 0; q < 45; ++q) accq[q] = 0.f;

  const float* Pb = P + (size_t)brb * EDz * TSTR;
  int e0 = esp * 40 + wave * 10;
#pragma unroll 2
  for (int i = 0; i < 10; ++i) {
    int e = e0 + i;
    const float* pr = Pb + (size_t)e * TSTR;
    float p0 = (t >= 3) ? pr[t - 3] : 0.f;
    float p1 = (t >= 2) ? pr[t - 2] : 0.f;
    float p2 = (t >= 1) ? pr[t - 1] : 0.f;
    float p3 = pr[t];
    float4 c4 = *(const float4*)(cw + e * 4);
    float a = cb[e] + c4.x * p0 + c4.y * p1 + c4.z * p2 + c4.w * p3;
    float sp = a / (1.f + __expf(-a));
    xp_t[((size_t)brb * EDz + e) * TSTR + t] = sp;
    const float* xq = xpj + e * 45;
#pragma unroll
    for (int q = 0; q < 45; ++q) accq[q] += sp * xq[q];
  }
#pragma unroll
  for (int q = 0; q < 45; ++q) sred[wave][lane][q] = accq[q];
  __syncthreads();
  if (wave < 2) {
#pragma unroll
    for (int q = 0; q < 45; ++q)
      sred[wave][lane][q] += sred[wave + 2][lane][q];
  }
  __syncthreads();
  if (wave == 0) {
    float* dp = dbcp + ((size_t)(esp * 8 + brb) * 45) * TSTR + t;
#pragma unroll
    for (int q = 0; q < 45; ++q)
      dp[(size_t)q * TSTR] = sred[0][lane][q] + sred[1][lane][q];
  }
}

// Sum ESP partials and finish dt / Bm / Cend with high TLP.
// grid = brb(8) x tc(8) x egrp(11) = 704 blocks, 256 threads.
// egrp 0..9: dt for 40 e's each. egrp 10: Bm_t (+Cend when tc==7).
__global__ __launch_bounds__(256) void k_dt2(
    const float* __restrict__ dbcp,
    const float* __restrict__ dtwf, const float* __restrict__ dtwb,
    const float* __restrict__ dtbf, const float* __restrict__ dtbb,
    float* __restrict__ dt_t, float* __restrict__ Bm_t,
    float* __restrict__ Cend) {
  int bid = blockIdx.x;
  int egrp = bid % 11;
  int rem = bid / 11;
  int tc = rem & 7, brb = rem >> 3;
  int br = brb >> 2;
  int tid = threadIdx.x;
  int wave = tid >> 6, lane = tid & 63;
  int t = tc * 64 + lane;
  const size_t espstr = (size_t)8 * 45 * TSTR;

  if (egrp == 10) {
    for (int idx = tid; idx < 16 * 64; idx += 256) {
      int n = idx >> 6, tl = idx & 63;
      size_t base = ((size_t)brb * 45 + 13 + n) * TSTR + tc * 64 + tl;
      float s = 0.f;
#pragma unroll
      for (int esp = 0; esp < ESP; ++esp) s += dbcp[base + esp * espstr];
      Bm_t[((size_t)brb * Nz + n) * TSTR + tc * 64 + tl] = s;
    }
    if (tc == 7 && tid < Nz) {
      size_t base = ((size_t)brb * 45 + 29 + tid) * TSTR + POSz;
      float s = 0.f;
#pragma unroll
      for (int esp = 0; esp < ESP; ++esp) s += dbcp[base + esp * espstr];
      Cend[brb * Nz + tid] = s;
    }
    return;
  }

  __shared__ float dfin[DTRz][64];
  for (int idx = tid; idx < DTRz * 64; idx += 256) {
    int q = idx >> 6, tl = idx & 63;
    size_t base = ((size_t)brb * 45 + q) * TSTR + tc * 64 + tl;
    float s = 0.f;
#pragma unroll
    for (int esp = 0; esp < ESP; ++esp) s += dbcp[base + esp * espstr];
    dfin[q][tl] = s;
  }
  __syncthreads();
  const float* dtw = br ? dtwb : dtwf;
  const float* dtb = br ? dtbb : dtbf;
  float dq[DTRz];
#pragma unroll
  for (int q = 0; q < DTRz; ++q) dq[q] = dfin[q][lane];
  int e0 = egrp * 40 + wave * 10;
#pragma unroll 2
  for (int i = 0; i < 10; ++i) {
    int e = e0 + i;
    float s = dtb[e];
#pragma unroll
    for (int q = 0; q < DTRz; ++q) s += dq[q] * dtw[q * EDz + e];
    float dtv = (s > 20.f) ? s : log1pf(__expf(s));
    dt_t[((size_t)brb * EDz + e) * TSTR + t] = dtv;
  }
}

// h[end,e,n] = sum_t exp(A_n*(Stot-S_t))*dt_t*Bm[t,n]*xp_t, lane-contiguous.
__global__ __launch_bounds__(64) void k_scan(
    const float* __restrict__ xp_t, const float* __restrict__ dt_t,
    const float* __restrict__ Bm_t, const float* __restrict__ Cend,
    const float* __restrict__ Alogf, const float* __restrict__ Alogb,
    const float* __restrict__ Dpf, const float* __restrict__ Dpb,
    const float* __restrict__ zbuf, const float* __restrict__ vbuf,
    float* __restrict__ ybuf) {
  int blk = blockIdx.x;
  int br = blk / (Bz * EDz);
  int rem = blk - br * (Bz * EDz);
  int b = rem / EDz, e = rem - b * EDz;
  int lane = threadIdx.x;
  const float* A_log = br ? Alogb : Alogf;
  const float* Dp = br ? Dpb : Dpf;
  float A[Nz];
  {
    const float4* ap = (const float4*)(A_log + e * Nz);
#pragma unroll
    for (int q = 0; q < 4; ++q) {
      float4 a4 = ap[q];
      A[q * 4 + 0] = -__expf(a4.x); A[q * 4 + 1] = -__expf(a4.y);
      A[q * 4 + 2] = -__expf(a4.z); A[q * 4 + 3] = -__expf(a4.w);
    }
  }
  size_t base = ((size_t)(br * Bz + b) * EDz + e) * TSTR;
  const float* dtp = dt_t + base;
  const float* xpp = xp_t + base;
  const float* bmp = Bm_t + (size_t)(br * Bz + b) * Nz * TSTR;
  float loc = 0.f;
#pragma unroll
  for (int c = 0; c < 8; ++c) {
    int t = c * 64 + lane;
    if (t < LPz) loc += dtp[t];
  }
  float Stot = wave_sum(loc);
  float acc[Nz];
#pragma unroll
  for (int n = 0; n < Nz; ++n) acc[n] = 0.f;
  float carry = 0.f;
  for (int c = 0; c < 8; ++c) {
    int t = c * 64 + lane;
    bool act = t < LPz;
    float dtt = 0.f, xv = 0.f;
    if (act) { dtt = dtp[t]; xv = xpp[t]; }
    float s = dtt;
#pragma unroll
    for (int o = 1; o < 64; o <<= 1) {
      float u = __shfl_up(s, o);
      s += (lane >= o) ? u : 0.f;
    }
    float S = carry + s;
    carry += __shfl(s, 63);
    float wt = dtt * xv;
    float decay = Stot - S;  // >= 0, A<0 => exp<=1
#pragma unroll
    for (int n = 0; n < Nz; ++n) {
      float bv = 0.f;
      if (act) bv = bmp[n * TSTR + t];
      acc[n] += __expf(A[n] * decay) * wt * bv;
    }
  }
#pragma unroll
  for (int o = 32; o; o >>= 1) {
#pragma unroll
    for (int n = 0; n < Nz; ++n) acc[n] += __shfl_xor(acc[n], o);
  }
  if (lane == 0) {
    float y = Dp[e] * xpp[LPz - 1];
#pragma unroll
    for (int n = 0; n < Nz; ++n) y += Cend[(br * Bz + b) * Nz + n] * acc[n];
    float zz = zbuf[((size_t)br * Bz + b) * EDz + e];
    float sz = zz / (1.f + __expf(-zz));
    ybuf[((size_t)br * Bz + b) * EDz + e] = y * sz * vbuf[e];
  }
}

__global__ __launch_bounds__(256) void k_final(
    const float* __restrict__ cls, const float* __restrict__ head_w,
    const float* __restrict__ head_b, const float* __restrict__ ybuf,
    float* __restrict__ out) {
  int tid = threadIdx.x;
  int b = tid >> 6, lane = tid & 63;
  float acc = 0.f;
  for (int e = lane; e < EDz; e += 64)
    acc += ybuf[(size_t)b * EDz + e] + ybuf[(size_t)(Bz + b) * EDz + e];
  for (int d = lane; d < Dz; d += 64) acc += cls[d] * head_w[d];
  acc = wave_sum(acc);
  if (lane == 0) out[b] = 1.f / (1.f + __expf(-(acc + head_b[0])));
}

extern "C" void kernel_launch(void* const* d_in, const int* in_sizes, int n_in,
                              void* d_out, int out_size, void* d_ws, size_t ws_size,
                              hipStream_t stream) {
  const float* input_ids = (const float*)d_in[0];
  const int* n_tweets = (const int*)d_in[1];
  const int* n_words = (const int*)d_in[2];
  const float* cls = (const float*)d_in[3];
  const float* w_attn = (const float*)d_in[4];
  const float* b_attn = (const float*)d_in[5];
  const float* norm_w = (const float*)d_in[6];
  const float* ip[2] = {(const float*)d_in[7], (const float*)d_in[15]};
  const float* cw[2] = {(const float*)d_in[8], (const float*)d_in[16]};
  const float* cb[2] = {(const float*)d_in[9], (const float*)d_in[17]};
  const float* xpj[2] = {(const float*)d_in[10], (const float*)d_in[18]};
  const float* dtw[2] = {(const float*)d_in[11], (const float*)d_in[19]};
  const float* dtbp[2] = {(const float*)d_in[12], (const float*)d_in[20]};
  const float* Alog[2] = {(const float*)d_in[13], (const float*)d_in[21]};
  const float* Dpp[2] = {(const float*)d_in[14], (const float*)d_in[22]};
  const float* out_proj = (const float*)d_in[23];
  const float* head_w = (const float*)d_in[24];
  const float* head_b = (const float*)d_in[25];
  float* out = (float*)d_out;

  float* ws = (float*)d_ws;
  float* xn = ws;                           // 800800
  float* Pbuf = xn + 800800;                // 1638400
  float* xp_t = Pbuf + 1638400;             // 1638400
  float* dt_t = xp_t + 1638400;             // 1638400
  float* Bm_t = dt_t + 1638400;             // 65536
  float* dbcp = Bm_t + 65536;               // 10*8*45*512 = 1843200
  float* Cend = dbcp + 1843200;             // 128
  float* zbuf = Cend + 128;                 // 3200
  float* vbuf = zbuf + 3200;                // 400
  float* ybuf = vbuf + 400;                 // 3200
  // total ~7.63M floats ~30.5 MB

  hipLaunchKernelGGL(k_front, dim3(9 + Bz * Tz), dim3(256), 0, stream,
                     input_ids, n_tweets, n_words, w_attn, b_attn, norm_w,
                     cls, out_proj, head_w, ip[0], ip[1], xn, zbuf, vbuf);
  hipLaunchKernelGGL(k_gemm, dim3(2 * Bz * 8 * 7), dim3(256), 0, stream,
                     xn, ip[0], ip[1], Pbuf);
  hipLaunchKernelGGL(k_mid, dim3(2 * Bz * 8 * ESP), dim3(256), 0, stream,
                     Pbuf, cw[0], cw[1], cb[0], cb[1], xpj[0], xpj[1],
                     xp_t, dbcp);
  hipLaunchKernelGGL(k_dt2, dim3(2 * Bz * 8 * 11), dim3(256), 0, stream,
                     dbcp, dtw[0], dtw[1], dtbp[0], dtbp[1],
                     dt_t, Bm_t, Cend);
  hipLaunchKernelGGL(k_scan, dim3(2 * Bz * EDz), dim3(64), 0, stream,
                     xp_t, dt_t, Bm_t, Cend, Alog[0], Alog[1], Dpp[0], Dpp[1],
                     zbuf, vbuf, ybuf);
  hipLaunchKernelGGL(k_final, dim3(1), dim3(256), 0, stream,
                     cls, head_w, head_b, ybuf, out);
}